// Round 1
// baseline (545.000 us; speedup 1.0000x reference)
//
#include <hip/hip_runtime.h>

typedef __bf16 bf16x2 __attribute__((ext_vector_type(2)));
typedef __bf16 bf16x8 __attribute__((ext_vector_type(8)));
typedef float  f32x4  __attribute__((ext_vector_type(4)));

// ---------------------------------------------------------------------------
// Complex 1x1 band conv as per-(n,l) real GEMM:
//   [vr; vi] = [[Wr, -Wi],[Wi, Wr]] * [ur; ui]   (128 x 128) x (128 x HW)
// Block: 128 f' rows x 128 pixels, K=128, 4 waves (2x2), mfma_f32_16x16x32_bf16.
// grid = (HW/128, 6, N)
__global__ __launch_bounds__(256)
void band_conv_kernel(const float* __restrict__ u, const float* __restrict__ g,
                      float* __restrict__ out, int HW) {
    __shared__ __bf16 sW[128 * 128];   // W'[f'][c'], 256B rows, XOR-swizzled
    __shared__ __bf16 sX[128 * 128];   // X[p][c'],  256B rows, XOR-swizzled

    const int t  = threadIdx.x;
    const int p0 = blockIdx.x << 7;
    const int l  = blockIdx.y;
    const int n  = blockIdx.z;

    // ---- stage W' from g (L,2,F,C): 2048 iters over (f, c-pair)
    const float* gr = g + (size_t)(l * 2 + 0) * 4096;
    const float* gi = g + (size_t)(l * 2 + 1) * 4096;
    for (int j = t; j < 2048; j += 256) {
        const int f  = j >> 5;
        const int cp = j & 31;
        const float2 vr = *(const float2*)(gr + (f << 6) + (cp << 1));
        const float2 vi = *(const float2*)(gi + (f << 6) + (cp << 1));
        const int swf = (f & 7) << 4;
        const int c2  = cp << 2;                    // byte offset of col pair
        char* b0 = (char*)sW + (f << 8);
        char* b1 = (char*)sW + ((f + 64) << 8);
        bf16x2 w00 = {(__bf16)vr.x, (__bf16)vr.y};
        bf16x2 w01 = {(__bf16)(-vi.x), (__bf16)(-vi.y)};
        bf16x2 w10 = {(__bf16)vi.x, (__bf16)vi.y};
        *(bf16x2*)(b0 + ((c2      ) ^ swf)) = w00;
        *(bf16x2*)(b0 + ((c2 + 128) ^ swf)) = w01;
        *(bf16x2*)(b1 + ((c2      ) ^ swf)) = w10;
        *(bf16x2*)(b1 + ((c2 + 128) ^ swf)) = w00;
    }

    // ---- stage X from u (N,C,L,H,W,2): coalesced float2 reads, transposed to [p][c']
    const size_t cstr = (size_t)6 * HW * 2;        // c stride in floats
    const float* ub = u + ((size_t)n * 64 * 6 + l) * HW * 2 + (size_t)p0 * 2;
    for (int j = t; j < 4096; j += 256) {
        const int cp = j >> 7;                     // c pair index
        const int pl = j & 127;
        const float* up = ub + (size_t)pl * 2 + (size_t)(cp * 2) * cstr;
        const float2 v0 = *(const float2*)(up);
        const float2 v1 = *(const float2*)(up + cstr);
        const int sw = (pl & 7) << 4;
        const int c2 = cp << 2;
        char* b0 = (char*)sX + (pl << 8);
        bf16x2 xr = {(__bf16)v0.x, (__bf16)v1.x};
        bf16x2 xi = {(__bf16)v0.y, (__bf16)v1.y};
        *(bf16x2*)(b0 + ((c2      ) ^ sw)) = xr;
        *(bf16x2*)(b0 + ((c2 + 128) ^ sw)) = xi;
    }
    __syncthreads();

    // ---- GEMM 128x128x128
    const int lane = t & 63;
    const int wid  = t >> 6;
    const int wm = wid >> 1, wn = wid & 1;
    const int lo = lane & 15, hi = lane >> 4;

    f32x4 acc[4][4];
    const f32x4 zero = {0.f, 0.f, 0.f, 0.f};
#pragma unroll
    for (int i = 0; i < 4; i++)
#pragma unroll
        for (int j = 0; j < 4; j++) acc[i][j] = zero;

    // wave's A rows: mt 0,1 -> real f-block (wm*32 .. +32), mt 2,3 -> imag partner (+64)
    int arow[4], brow[4];
#pragma unroll
    for (int mt = 0; mt < 4; mt++) arow[mt] = wm * 32 + (mt & 1) * 16 + (mt >> 1) * 64 + lo;
#pragma unroll
    for (int nt = 0; nt < 4; nt++) brow[nt] = wn * 64 + nt * 16 + lo;

#pragma unroll
    for (int kk = 0; kk < 4; kk++) {
        const int kb = (kk * 32 + hi * 8) << 1;    // byte offset of k chunk in a row
        bf16x8 a[4], b[4];
#pragma unroll
        for (int mt = 0; mt < 4; mt++)
            a[mt] = *(const bf16x8*)((const char*)sW + (arow[mt] << 8) + (kb ^ ((arow[mt] & 7) << 4)));
#pragma unroll
        for (int nt = 0; nt < 4; nt++)
            b[nt] = *(const bf16x8*)((const char*)sX + (brow[nt] << 8) + (kb ^ ((brow[nt] & 7) << 4)));
#pragma unroll
        for (int mt = 0; mt < 4; mt++)
#pragma unroll
            for (int nt = 0; nt < 4; nt++)
                acc[mt][nt] = __builtin_amdgcn_mfma_f32_16x16x32_bf16(a[mt], b[nt], acc[mt][nt], 0, 0, 0);
    }

    // ---- epilogue: coalesced float2 {re, im} stores
    const size_t HW6 = (size_t)HW * 6;
    const size_t ob  = ((size_t)n * 384 + l) * HW;   // (n*64*6 + l) * HW
#pragma unroll
    for (int mt = 0; mt < 2; mt++)
#pragma unroll
        for (int nt = 0; nt < 4; nt++)
#pragma unroll
            for (int r = 0; r < 4; r++) {
                const int fq = wm * 32 + mt * 16 + hi * 4 + r;   // D row = (lane>>4)*4 + reg  [m89]
                const int p  = p0 + wn * 64 + nt * 16 + lo;      // D col = lane&15
                float2 o;
                o.x = acc[mt][nt][r];
                o.y = acc[mt + 2][nt][r];
                *(float2*)(out + ((ob + (size_t)fq * HW6 + p) << 1)) = o;
            }
}

// ---------------------------------------------------------------------------
// v_lp: exact f32 3x3 conv, pad 1. One output row per block, grid (32, 16).
// LDS: 3 input rows (all 64 c) with x-halo at col offset +4 (keeps f32x4 reads
// 16B-aligned), per-c weight slice staged to LDS (weights are L2-hot).
__global__ __launch_bounds__(256)
void lp_conv_kernel(const float* __restrict__ in, const float* __restrict__ w,
                    float* __restrict__ out) {
    __shared__ float s_in[3][64][40];
    __shared__ float s_w[64][9];

    const int t  = threadIdx.x;
    const int y0 = blockIdx.x;
    const int n  = blockIdx.y;

    for (int j = t; j < 3 * 64 * 32; j += 256) {
        const int yy = j >> 11;
        const int c  = (j >> 5) & 63;
        const int x  = j & 31;
        const int yi = y0 - 1 + yy;
        float v = 0.f;
        if (yi >= 0 && yi < 32) v = in[(((n << 6) | c) << 10) + (yi << 5) + x];
        s_in[yy][c][x + 4] = v;
    }
    for (int j = t; j < 3 * 64 * 8; j += 256) {   // zero the x-halo columns
        const int yy = j >> 9;
        const int c  = (j >> 3) & 63;
        const int h  = j & 7;
        s_in[yy][c][h < 4 ? h : h + 32] = 0.f;
    }

    const int f  = t >> 2;
    const int x0 = (t & 3) << 3;

    float acc[8];
#pragma unroll
    for (int i = 0; i < 8; i++) acc[i] = 0.f;

    for (int c = 0; c < 64; c++) {
        __syncthreads();                           // prev compute done before w restage
        for (int j = t; j < 576; j += 256) {
            const int ff = j / 9, tap = j % 9;
            s_w[ff][tap] = w[ff * 576 + c * 9 + tap];
        }
        __syncthreads();                           // (also covers s_in on c==0)

        float wt[9];
#pragma unroll
        for (int i = 0; i < 9; i++) wt[i] = s_w[f][i];

        float win[3][16];
#pragma unroll
        for (int yy = 0; yy < 3; yy++) {
            const f32x4* rp = (const f32x4*)&s_in[yy][c][x0];
#pragma unroll
            for (int k = 0; k < 4; k++) {
                const f32x4 v = rp[k];
#pragma unroll
                for (int e = 0; e < 4; e++) win[yy][k * 4 + e] = v[e];
            }
        }
#pragma unroll
        for (int dy = 0; dy < 3; dy++)
#pragma unroll
            for (int dx = 0; dx < 3; dx++) {
                const float wv = wt[dy * 3 + dx];
#pragma unroll
                for (int ox = 0; ox < 8; ox++)
                    acc[ox] += wv * win[dy][ox + dx + 3];   // taps use cols x0+3..x0+12
            }
    }

    const int ob = (((n << 6) | f) << 10) + (y0 << 5) + x0;
#pragma unroll
    for (int k = 0; k < 2; k++) {
        const f32x4 v = {acc[k * 4 + 0], acc[k * 4 + 1], acc[k * 4 + 2], acc[k * 4 + 3]};
        *(f32x4*)(out + ob + k * 4) = v;
    }
}

// ---------------------------------------------------------------------------
extern "C" void kernel_launch(void* const* d_in, const int* in_sizes, int n_in,
                              void* d_out, int out_size, void* d_ws, size_t ws_size,
                              hipStream_t stream) {
    const float* u_lp = (const float*)d_in[0];
    const float* u0   = (const float*)d_in[1];
    const float* u1   = (const float*)d_in[2];
    const float* g_lp = (const float*)d_in[3];
    const float* g0   = (const float*)d_in[4];
    const float* g1   = (const float*)d_in[5];
    float* out = (float*)d_out;

    // output tuple layout: v_lp [0, 1048576), v0 [1048576, 51380224), v1 [51380224, ...)
    lp_conv_kernel<<<dim3(32, 16, 1), dim3(256), 0, stream>>>(u_lp, g_lp, out);
    band_conv_kernel<<<dim3(32, 6, 16), dim3(256), 0, stream>>>(u0, g0, out + 1048576, 4096);
    band_conv_kernel<<<dim3(8, 6, 16), dim3(256), 0, stream>>>(u1, g1, out + 51380224, 1024);
}